// Round 5
// baseline (437.119 us; speedup 1.0000x reference)
//
#include <hip/hip_runtime.h>
#include <hip/hip_bf16.h>

// Problem constants
static constexpr int BB = 2;      // batch
static constexpr int SS = 2048;   // seq len
static constexpr int DD = 2048;   // model dim
static constexpr int HH = 16;     // heads
static constexpr int HD = 128;    // head dim

typedef __bf16 bf16_t;
typedef __bf16 bf16x8 __attribute__((ext_vector_type(8)));
typedef __bf16 bf16x4 __attribute__((ext_vector_type(4)));
typedef float  floatx4 __attribute__((ext_vector_type(4)));

// Async global->LDS, 16B per lane. LDS dest is wave-uniform base + lane*16.
__device__ __forceinline__ void gl2lds16(const bf16_t* g, bf16_t* l) {
    __builtin_amdgcn_global_load_lds(
        (const __attribute__((address_space(1))) void*)g,
        (__attribute__((address_space(3))) void*)l, 16, 0, 0);
}

// ---------------------------------------------------------------------------
// Cast x (fp32) -> bf16, vectorized 4 elements/thread
// ---------------------------------------------------------------------------
__global__ void cast_x_kernel(const float* __restrict__ x, bf16_t* __restrict__ xb) {
    int i = blockIdx.x * 256 + threadIdx.x;
    float4 v = ((const float4*)x)[i];
    bf16x4 o;
    o.x = (bf16_t)v.x; o.y = (bf16_t)v.y; o.z = (bf16_t)v.z; o.w = (bf16_t)v.w;
    ((bf16x4*)xb)[i] = o;
}

// ---------------------------------------------------------------------------
// Transpose + cast one DxD fp32 weight into bf16 W^T (row n holds W[:,n])
// block (32,8), grid (D/32, D/32)
// ---------------------------------------------------------------------------
__global__ void transpose_cast_kernel(const float* __restrict__ W, bf16_t* __restrict__ Wt) {
    __shared__ float tile[32][33];
    int bx = blockIdx.x * 32;   // n
    int by = blockIdx.y * 32;   // k
    int tx = threadIdx.x, ty = threadIdx.y;
#pragma unroll
    for (int j = 0; j < 4; ++j)
        tile[ty + j * 8][tx] = W[(size_t)(by + ty + j * 8) * DD + bx + tx];
    __syncthreads();
#pragma unroll
    for (int j = 0; j < 4; ++j)
        Wt[(size_t)(bx + ty + j * 8) * DD + by + tx] = (bf16_t)tile[tx][ty + j * 8];
}

// ---------------------------------------------------------------------------
// bf16 GEMM, C[M x N] = A[M x K] @ Bt[N x K]^T.  128x128 tile, 256 threads,
// m97 structure: unpadded 128x64 LDS tiles staged via global_load_lds w=16,
// XOR chunk swizzle so ds_read_b128 hits the 8-beat minimum.
// MODE 0: QKV epilogue -> scatter bf16 Q/K/V [b][h][s][d]
// MODE 1: plain fp32 epilogue -> Cf[m*N+n]
// ---------------------------------------------------------------------------
template <int MODE>
__global__ __launch_bounds__(256, 2) void gemm_bt_kernel(
    const bf16_t* __restrict__ A, const bf16_t* __restrict__ Bt,
    float* __restrict__ Cf, bf16_t* __restrict__ Qw, bf16_t* __restrict__ Kw,
    bf16_t* __restrict__ Vw, int N, int K) {
    __shared__ __align__(16) bf16_t As[128 * 64];
    __shared__ __align__(16) bf16_t Bs[128 * 64];

    const int t = threadIdx.x;
    const int lane = t & 63;
    const int wave = t >> 6;
    const int lrow = lane & 15;   // m (A) / n (B) within 16
    const int lkq  = lane >> 4;   // k-quad
    const int wm = (wave & 1) * 64;
    const int wn = (wave >> 1) * 64;
    const int m0 = blockIdx.y * 128;
    const int n0 = blockIdx.x * 128;

    floatx4 acc[4][4];
#pragma unroll
    for (int i = 0; i < 4; ++i)
#pragma unroll
        for (int j = 0; j < 4; ++j) acc[i][j] = (floatx4)0.0f;

    // staging geometry: per instr a wave moves 8 rows x 64 cols (1024B).
    const int srow  = lane >> 3;                    // row within 8
    const int sch   = (lane & 7) ^ srow;            // swizzled global chunk

    for (int k0 = 0; k0 < K; k0 += 64) {
        __syncthreads();
#pragma unroll
        for (int p = 0; p < 4; ++p) {
            int r = wave * 32 + p * 8 + srow;
            gl2lds16(A  + (size_t)(m0 + r) * K + k0 + sch * 8, As + (wave * 32 + p * 8) * 64);
            gl2lds16(Bt + (size_t)(n0 + r) * K + k0 + sch * 8, Bs + (wave * 32 + p * 8) * 64);
        }
        __syncthreads();
#pragma unroll
        for (int ks = 0; ks < 2; ++ks) {
            bf16x8 af[4], bg[4];
#pragma unroll
            for (int i = 0; i < 4; ++i) {
                int pos = ((ks * 4 + lkq) ^ (lrow & 7)) * 8;
                af[i] = *(const bf16x8*)(As + (wm + i * 16 + lrow) * 64 + pos);
                bg[i] = *(const bf16x8*)(Bs + (wn + i * 16 + lrow) * 64 + pos);
            }
#pragma unroll
            for (int i = 0; i < 4; ++i)
#pragma unroll
                for (int j = 0; j < 4; ++j)
                    acc[i][j] = __builtin_amdgcn_mfma_f32_16x16x32_bf16(af[i], bg[j], acc[i][j], 0, 0, 0);
        }
    }

    // Epilogue. C/D layout (verified m89): col = lane&15, row = (lane>>4)*4 + reg.
#pragma unroll
    for (int i = 0; i < 4; ++i)
#pragma unroll
        for (int j = 0; j < 4; ++j)
#pragma unroll
            for (int r = 0; r < 4; ++r) {
                int m = m0 + wm + i * 16 + lkq * 4 + r;
                int n = n0 + wn + j * 16 + lrow;
                float v = acc[i][j][r];
                if (MODE == 1) {
                    Cf[(size_t)m * N + n] = v;
                } else {
                    bf16_t bv = (bf16_t)v;
                    int b = m >> 11, s = m & (SS - 1);
                    int nn = n & (DD - 1);
                    int h = nn >> 7, d = nn & 127;
                    size_t off = (((size_t)b * HH + h) * SS + s) * HD + d;
                    if (n < DD)            Qw[off] = bv;
                    else if (n < 2 * DD)   Kw[off] = bv;
                    else                   Vw[off] = bv;
                }
            }
}

// ---------------------------------------------------------------------------
// In-place interleaved RoPE on Q and K, layout [b][h][s][d], fp32 math.
// ---------------------------------------------------------------------------
__global__ void rope_kernel(bf16_t* __restrict__ Qw, bf16_t* __restrict__ Kw) {
    int idx = blockIdx.x * 256 + threadIdx.x;   // < BB*HH*SS*64
    int i  = idx & 63;
    int s  = (idx >> 6) & (SS - 1);
    int bh = idx >> 17;
    float inv = expf(-(float)(2 * i) * (9.210340371976184f / 128.0f));
    float ang = (float)s * inv;
    float c = cosf(ang), sn = sinf(ang);
    size_t base = ((size_t)bh * SS + s) * HD + 2 * i;
    float q1 = (float)Qw[base], q2 = (float)Qw[base + 1];
    Qw[base]     = (bf16_t)(q1 * c - q2 * sn);
    Qw[base + 1] = (bf16_t)(q1 * sn + q2 * c);
    float k1 = (float)Kw[base], k2 = (float)Kw[base + 1];
    Kw[base]     = (bf16_t)(k1 * c - k2 * sn);
    Kw[base + 1] = (bf16_t)(k1 * sn + k2 * c);
}

// ---------------------------------------------------------------------------
// V transpose: Vw [bh][s][d] -> Vt [bh][d][s'], where s' is PERMUTED within
// each 64-s chunk so flash's PV B-operand reads the MFMA k-slot order that
// matches the in-register P fragments (no P LDS round-trip needed).
// Slot mapping: LDS/global position p = (k2:1)(lkq:2)(a:1)(b:2) holds
// s = (k2:1)(a:1)(lkq:2)(b:2).  64x64 tiles via LDS (pad 65), coalesced
// 16B+ on both global sides.  grid (SS/64, HD/64, BB*HH), block 256.
// ---------------------------------------------------------------------------
__global__ void vtrans_kernel(const bf16_t* __restrict__ Vw, bf16_t* __restrict__ Vt) {
    __shared__ unsigned short lds[64][65];
    const int t = threadIdx.x;
    const int s0 = blockIdx.x * 64, d0 = blockIdx.y * 64, bh = blockIdx.z;
    const bf16_t* src = Vw + ((size_t)bh * SS + s0) * HD + d0;
    bf16_t* dst = Vt + ((size_t)bh * HD + d0) * SS + s0;
#pragma unroll
    for (int p = 0; p < 2; ++p) {
        int c = p * 256 + t;
        int s = c >> 3, ch = c & 7;                  // 8 chunks of 16B per 64-d row
        uint4 v = *(const uint4*)(src + (size_t)s * HD + ch * 8);
        const unsigned short* pv = (const unsigned short*)&v;
#pragma unroll
        for (int e = 0; e < 8; ++e) lds[ch * 8 + e][s] = pv[e];
    }
    __syncthreads();
    {
        int d = t >> 2, sb = (t & 3) * 16;           // 16 s-elements = 32B per thread
        uint4 o[2];
        unsigned short* po = (unsigned short*)o;
#pragma unroll
        for (int e = 0; e < 16; ++e) {
            int p = sb + e;
            // p = (k2)(lkq:2)(a)(b:2)  ->  s = (k2)(a)(lkq:2)(b:2)
            int s = (p & ~31) | ((p & 4) << 2) | ((p & 24) >> 1) | (p & 3);
            po[e] = lds[d][s];
        }
        *(uint4*)(dst + (size_t)d * SS + sb) = o[0];
        *(uint4*)(dst + (size_t)d * SS + sb + 8) = o[1];
    }
}

// ---------------------------------------------------------------------------
// Causal flash attention, S^T formulation, 64-q tile, REGISTER-P +
// COUNTED-VMCNT DOUBLE-BUFFER version (guide T3+T4 minimum form).
// Round-4 post-mortem: 2->4 blocks/CU bought only 3% (118->115us).  Root
// cause finally identified: EVERY version so far drained vmcnt to 0 at a
// __syncthreads() before compute -- including round-1's "double-buffered"
// variant, whose barrier waited for the prefetch loads it had just issued
// (HIP __syncthreads emits s_waitcnt vmcnt(0) lgkmcnt(0); guide Sec.5 "the
// barrier drain is the ~20% stall").  So each of the longest block's 32
// chunks paid a serial HBM/L2 round trip.
// Round-5 structure (one change): per chunk
//   stage(kc+1)->buf^1 ; asm s_waitcnt vmcnt(8) ; s_barrier   // #A
//   compute(kc) from buf ; s_barrier                          // #B
// The counted vmcnt(8) only waits for stage(kc) (issued one full compute
// phase earlier, already home); the 8 prefetch loads stay in flight across
// both raw barriers.  Race audit: #B separates all compute(kc) ds_reads
// (retired -- consumed by MFMAs) from stage(kc+2) writes to the same parity
// buffer; per-wave vmcnt + #A makes buf[cur] globally ready.  LDS 64KB ->
// 2 blocks/CU (round-4 proved block count isn't the lever; chain length is).
// ---------------------------------------------------------------------------
__global__ __launch_bounds__(256, 2) void flash_attn_kernel(
    const bf16_t* __restrict__ Qw, const bf16_t* __restrict__ Kw,
    const bf16_t* __restrict__ Vtw, bf16_t* __restrict__ Attn) {
    __shared__ __align__(16) bf16_t Ks[2][64 * 128];   // [k][d], chunks swizzled
    __shared__ __align__(16) bf16_t Vs[2][128 * 64];   // [d][s'], chunks swizzled

    const int t = threadIdx.x;
    const int lane = t & 63;
    const int wave = t >> 6;
    const int lrow = lane & 15;
    const int lkq  = lane >> 4;
    const int bx = blockIdx.x;                        // 0..31
    const int qtile = (bx & 1) ? (bx >> 1) : (31 - (bx >> 1));   // longest first
    const int bh = blockIdx.y;
    const int q0 = qtile * 64;

    const bf16_t* Qbh = Qw + (size_t)bh * SS * HD;
    const bf16_t* Kbh = Kw + (size_t)bh * SS * HD;
    const bf16_t* Vbh = Vtw + (size_t)bh * HD * SS;

    const int qb = q0 + wave * 16;                    // this wave's q-set base

    // staging geometry (per chunk, 4+4 instrs per wave)
    const int krow = wave * 16 + (lane >> 4);         // + p*4, K rows
    const int kgch = (lane & 15);                     // ^ (row&7)
    const int vrow = wave * 32 + (lane >> 3);         // + p*8, V rows
    const int vgch = (lane & 7);                      // ^ (row&7)

    // Q fragments (B-operand layout: n=lane&15=q, k=quad*8+j), scale*log2e folded
    const float qscale = 0.08838834764831845f * 1.4426950408889634f;
    bf16x8 qf[4];
#pragma unroll
    for (int kc4 = 0; kc4 < 4; ++kc4) {
        qf[kc4] = *(const bf16x8*)(Qbh + (size_t)(qb + lrow) * HD + kc4 * 32 + lkq * 8);
#pragma unroll
        for (int e = 0; e < 8; ++e) qf[kc4][e] = (bf16_t)((float)qf[kc4][e] * qscale);
    }

    floatx4 oacc[8];
#pragma unroll
    for (int i = 0; i < 8; ++i) oacc[i] = (floatx4)0.0f;
    float m_i = -1e30f;
    float l_i = 0.0f;

    const int nch = qtile + 1;

    // prologue: stage chunk 0 into buffer 0
#pragma unroll
    for (int p = 0; p < 4; ++p) {
        int row = krow + p * 4;
        gl2lds16(Kbh + (size_t)row * HD + (kgch ^ (row & 7)) * 8,
                 Ks[0] + (wave * 16 + p * 4) * 128);
    }
#pragma unroll
    for (int p = 0; p < 4; ++p) {
        int row = vrow + p * 8;
        gl2lds16(Vbh + (size_t)row * SS + (vgch ^ (row & 7)) * 8,
                 Vs[0] + (wave * 32 + p * 8) * 64);
    }

    for (int kc = 0; kc < nch; ++kc) {
        const int cur = kc & 1;
        // issue next chunk's staging; counted wait only drains stage(kc)
        if (kc + 1 < nch) {
            const int nb = cur ^ 1;
            const size_t kco = (size_t)(kc + 1) * 64;
#pragma unroll
            for (int p = 0; p < 4; ++p) {
                int row = krow + p * 4;
                gl2lds16(Kbh + (kco + row) * HD + (kgch ^ (row & 7)) * 8,
                         Ks[nb] + (wave * 16 + p * 4) * 128);
            }
#pragma unroll
            for (int p = 0; p < 4; ++p) {
                int row = vrow + p * 8;
                gl2lds16(Vbh + (size_t)row * SS + kco + (vgch ^ (row & 7)) * 8,
                         Vs[nb] + (wave * 32 + p * 8) * 64);
            }
            asm volatile("s_waitcnt vmcnt(8)" ::: "memory");
        } else {
            asm volatile("s_waitcnt vmcnt(0)" ::: "memory");
        }
        __builtin_amdgcn_s_barrier();                 // #A: buf[cur] ready

        const bf16_t* Ksc = Ks[cur];
        const bf16_t* Vsc = Vs[cur];

        // S^T[64k x 16q]
        floatx4 sacc[4];
#pragma unroll
        for (int i = 0; i < 4; ++i) sacc[i] = (floatx4)0.0f;
#pragma unroll
        for (int nf = 0; nf < 4; ++nf)
#pragma unroll
            for (int kc4 = 0; kc4 < 4; ++kc4) {
                bf16x8 kf = *(const bf16x8*)(Ksc + (nf * 16 + lrow) * 128 +
                                             (((kc4 * 4 + lkq) ^ (lrow & 7)) * 8));
                sacc[nf] = __builtin_amdgcn_mfma_f32_16x16x32_bf16(kf, qf[kc4], sacc[nf], 0, 0, 0);
            }

        // softmax; P A-fragments built by pure in-register convert:
        // pa[k2][j] = P[q=lrow][k=32*k2+16*(j>>2)+4*lkq+(j&3)] = sacc[2k2+(j>>2)][j&3]
        const int qg = qb + lrow;
        float mx = m_i;
        if (kc == nch - 1) {
            // diagonal chunk: causal mask + max
#pragma unroll
            for (int nf = 0; nf < 4; ++nf)
#pragma unroll
                for (int r = 0; r < 4; ++r) {
                    int kg = kc * 64 + nf * 16 + lkq * 4 + r;
                    float sv = (kg > qg) ? -1e30f : sacc[nf][r];
                    sacc[nf][r] = sv;
                    mx = fmaxf(mx, sv);
                }
        } else {
#pragma unroll
            for (int nf = 0; nf < 4; ++nf)
#pragma unroll
                for (int r = 0; r < 4; ++r) mx = fmaxf(mx, sacc[nf][r]);
        }
        mx = fmaxf(mx, __shfl_xor(mx, 16));
        mx = fmaxf(mx, __shfl_xor(mx, 32));
        float alpha = exp2f(m_i - mx);
        m_i = mx;

        float rs = 0.0f;
#pragma unroll
        for (int nf = 0; nf < 4; ++nf)
#pragma unroll
            for (int r = 0; r < 4; ++r) {
                float pv = exp2f(sacc[nf][r] - mx);
                sacc[nf][r] = pv;
                rs += pv;
            }
        rs += __shfl_xor(rs, 16);
        rs += __shfl_xor(rs, 32);
        l_i = l_i * alpha + rs;

        // rescale O only if some lane's max moved (exact: exp2f(0)==1)
        if (__ballot(alpha < 1.0f)) {
            float av[4];
#pragma unroll
            for (int r = 0; r < 4; ++r) av[r] = __shfl(alpha, lkq * 4 + r);
#pragma unroll
            for (int nf8 = 0; nf8 < 8; ++nf8)
#pragma unroll
                for (int r = 0; r < 4; ++r) oacc[nf8][r] *= av[r];
        }

        // in-register P -> A-fragment (slot order matches permuted V^T)
        bf16x8 pa[2];
#pragma unroll
        for (int k2 = 0; k2 < 2; ++k2) {
            bf16x8 t8;
#pragma unroll
            for (int j = 0; j < 8; ++j)
                t8[j] = (bf16_t)sacc[2 * k2 + (j >> 2)][j & 3];
            pa[k2] = t8;
        }

        // PV
#pragma unroll
        for (int nf8 = 0; nf8 < 8; ++nf8)
#pragma unroll
            for (int k2 = 0; k2 < 2; ++k2) {
                bf16x8 vf = *(const bf16x8*)(Vsc + (nf8 * 16 + lrow) * 64 +
                                             (((k2 * 4 + lkq) ^ (lrow & 7)) * 8));
                oacc[nf8] = __builtin_amdgcn_mfma_f32_16x16x32_bf16(pa[k2], vf, oacc[nf8], 0, 0, 0);
            }

        __builtin_amdgcn_s_barrier();                 // #B: reads of buf[cur] done
    }

    // finalize: O /= l, write attn[b][s][h*128+d] (bf16)
    int bb = bh >> 4, h = bh & 15;
#pragma unroll
    for (int r = 0; r < 4; ++r) {
        float invl = 1.0f / __shfl(l_i, lkq * 4 + r);
        int q = qb + lkq * 4 + r;
#pragma unroll
        for (int nf8 = 0; nf8 < 8; ++nf8)
            Attn[((size_t)bb * SS + q) * DD + h * HD + nf8 * 16 + lrow] =
                (bf16_t)(oacc[nf8][r] * invl);
    }
}

// ---------------------------------------------------------------------------
extern "C" void kernel_launch(void* const* d_in, const int* in_sizes, int n_in,
                              void* d_out, int out_size, void* d_ws, size_t ws_size,
                              hipStream_t stream) {
    const float* x  = (const float*)d_in[0];
    const float* Wq = (const float*)d_in[1];
    const float* Wk = (const float*)d_in[2];
    const float* Wv = (const float*)d_in[3];
    const float* Wo = (const float*)d_in[4];
    float* out = (float*)d_out;

    bf16_t* p = (bf16_t*)d_ws;
    bf16_t* Xb    = p; p += (size_t)BB * SS * DD;
    bf16_t* Wqkvt = p; p += (size_t)3 * DD * DD;
    bf16_t* Wot   = p; p += (size_t)DD * DD;
    bf16_t* Qw    = p; p += (size_t)BB * HH * SS * HD;
    bf16_t* Kw    = p; p += (size_t)BB * HH * SS * HD;
    bf16_t* Vtw   = p; p += (size_t)BB * HH * SS * HD;
    bf16_t* Attn  = p; p += (size_t)BB * SS * DD;
    // V natural layout lives in the Attn region (dead until flash writes it):
    bf16_t* Vw = Attn;

    cast_x_kernel<<<(BB * SS * DD / 4) / 256, 256, 0, stream>>>(x, Xb);

    dim3 tb(32, 8), tg(DD / 32, DD / 32);
    transpose_cast_kernel<<<tg, tb, 0, stream>>>(Wq, Wqkvt);
    transpose_cast_kernel<<<tg, tb, 0, stream>>>(Wk, Wqkvt + (size_t)DD * DD);
    transpose_cast_kernel<<<tg, tb, 0, stream>>>(Wv, Wqkvt + (size_t)2 * DD * DD);
    transpose_cast_kernel<<<tg, tb, 0, stream>>>(Wo, Wot);

    // QKV: [4096 x 2048] @ [2048 x 6144] -> Q/K/V (all natural [bh][s][d])
    gemm_bt_kernel<0><<<dim3(3 * DD / 128, BB * SS / 128), 256, 0, stream>>>(
        Xb, Wqkvt, nullptr, Qw, Kw, Vw, 3 * DD, DD);

    rope_kernel<<<(BB * HH * SS * 64) / 256, 256, 0, stream>>>(Qw, Kw);

    // V [bh][s][d] -> Vt [bh][d][s-permuted], coalesced LDS transpose
    vtrans_kernel<<<dim3(SS / 64, HD / 64, BB * HH), 256, 0, stream>>>(Vw, Vtw);

    // 64-q tiles: 1024 blocks
    flash_attn_kernel<<<dim3(SS / 64, BB * HH), 256, 0, stream>>>(Qw, Kw, Vtw, Attn);

    // out = attn @ Wo : [4096 x 2048] @ [2048 x 2048] -> fp32
    gemm_bt_kernel<1><<<dim3(DD / 128, BB * SS / 128), 256, 0, stream>>>(
        Attn, Wot, out, nullptr, nullptr, nullptr, DD, DD);
}

// Round 6
// 392.153 us; speedup vs baseline: 1.1147x; 1.1147x over previous
//
#include <hip/hip_runtime.h>
#include <hip/hip_bf16.h>

// Problem constants
static constexpr int BB = 2;      // batch
static constexpr int SS = 2048;   // seq len
static constexpr int DD = 2048;   // model dim
static constexpr int HH = 16;     // heads
static constexpr int HD = 128;    // head dim

typedef __bf16 bf16_t;
typedef __bf16 bf16x8 __attribute__((ext_vector_type(8)));
typedef __bf16 bf16x4 __attribute__((ext_vector_type(4)));
typedef float  floatx4 __attribute__((ext_vector_type(4)));

// Async global->LDS, 16B per lane. LDS dest is wave-uniform base + lane*16.
__device__ __forceinline__ void gl2lds16(const bf16_t* g, bf16_t* l) {
    __builtin_amdgcn_global_load_lds(
        (const __attribute__((address_space(1))) void*)g,
        (__attribute__((address_space(3))) void*)l, 16, 0, 0);
}

// ---------------------------------------------------------------------------
// Cast x (fp32) -> bf16, vectorized 4 elements/thread
// ---------------------------------------------------------------------------
__global__ void cast_x_kernel(const float* __restrict__ x, bf16_t* __restrict__ xb) {
    int i = blockIdx.x * 256 + threadIdx.x;
    float4 v = ((const float4*)x)[i];
    bf16x4 o;
    o.x = (bf16_t)v.x; o.y = (bf16_t)v.y; o.z = (bf16_t)v.z; o.w = (bf16_t)v.w;
    ((bf16x4*)xb)[i] = o;
}

// ---------------------------------------------------------------------------
// Transpose + cast one DxD fp32 weight into bf16 W^T (row n holds W[:,n])
// block (32,8), grid (D/32, D/32)
// ---------------------------------------------------------------------------
__global__ void transpose_cast_kernel(const float* __restrict__ W, bf16_t* __restrict__ Wt) {
    __shared__ float tile[32][33];
    int bx = blockIdx.x * 32;   // n
    int by = blockIdx.y * 32;   // k
    int tx = threadIdx.x, ty = threadIdx.y;
#pragma unroll
    for (int j = 0; j < 4; ++j)
        tile[ty + j * 8][tx] = W[(size_t)(by + ty + j * 8) * DD + bx + tx];
    __syncthreads();
#pragma unroll
    for (int j = 0; j < 4; ++j)
        Wt[(size_t)(bx + ty + j * 8) * DD + by + tx] = (bf16_t)tile[tx][ty + j * 8];
}

// ---------------------------------------------------------------------------
// bf16 GEMM, C[M x N] = A[M x K] @ Bt[N x K]^T.  128x128 tile, 256 threads,
// m97 structure: unpadded 128x64 LDS tiles staged via global_load_lds w=16,
// XOR chunk swizzle so ds_read_b128 hits the 8-beat minimum.
// MODE 0: QKV epilogue -> scatter bf16 Q/K/V [b][h][s][d]
// MODE 1: plain fp32 epilogue -> Cf[m*N+n]
// ---------------------------------------------------------------------------
template <int MODE>
__global__ __launch_bounds__(256, 2) void gemm_bt_kernel(
    const bf16_t* __restrict__ A, const bf16_t* __restrict__ Bt,
    float* __restrict__ Cf, bf16_t* __restrict__ Qw, bf16_t* __restrict__ Kw,
    bf16_t* __restrict__ Vw, int N, int K) {
    __shared__ __align__(16) bf16_t As[128 * 64];
    __shared__ __align__(16) bf16_t Bs[128 * 64];

    const int t = threadIdx.x;
    const int lane = t & 63;
    const int wave = t >> 6;
    const int lrow = lane & 15;   // m (A) / n (B) within 16
    const int lkq  = lane >> 4;   // k-quad
    const int wm = (wave & 1) * 64;
    const int wn = (wave >> 1) * 64;
    const int m0 = blockIdx.y * 128;
    const int n0 = blockIdx.x * 128;

    floatx4 acc[4][4];
#pragma unroll
    for (int i = 0; i < 4; ++i)
#pragma unroll
        for (int j = 0; j < 4; ++j) acc[i][j] = (floatx4)0.0f;

    // staging geometry: per instr a wave moves 8 rows x 64 cols (1024B).
    const int srow  = lane >> 3;                    // row within 8
    const int sch   = (lane & 7) ^ srow;            // swizzled global chunk

    for (int k0 = 0; k0 < K; k0 += 64) {
        __syncthreads();
#pragma unroll
        for (int p = 0; p < 4; ++p) {
            int r = wave * 32 + p * 8 + srow;
            gl2lds16(A  + (size_t)(m0 + r) * K + k0 + sch * 8, As + (wave * 32 + p * 8) * 64);
            gl2lds16(Bt + (size_t)(n0 + r) * K + k0 + sch * 8, Bs + (wave * 32 + p * 8) * 64);
        }
        __syncthreads();
#pragma unroll
        for (int ks = 0; ks < 2; ++ks) {
            bf16x8 af[4], bg[4];
#pragma unroll
            for (int i = 0; i < 4; ++i) {
                int pos = ((ks * 4 + lkq) ^ (lrow & 7)) * 8;
                af[i] = *(const bf16x8*)(As + (wm + i * 16 + lrow) * 64 + pos);
                bg[i] = *(const bf16x8*)(Bs + (wn + i * 16 + lrow) * 64 + pos);
            }
#pragma unroll
            for (int i = 0; i < 4; ++i)
#pragma unroll
                for (int j = 0; j < 4; ++j)
                    acc[i][j] = __builtin_amdgcn_mfma_f32_16x16x32_bf16(af[i], bg[j], acc[i][j], 0, 0, 0);
        }
    }

    // Epilogue. C/D layout (verified m89): col = lane&15, row = (lane>>4)*4 + reg.
#pragma unroll
    for (int i = 0; i < 4; ++i)
#pragma unroll
        for (int j = 0; j < 4; ++j)
#pragma unroll
            for (int r = 0; r < 4; ++r) {
                int m = m0 + wm + i * 16 + lkq * 4 + r;
                int n = n0 + wn + j * 16 + lrow;
                float v = acc[i][j][r];
                if (MODE == 1) {
                    Cf[(size_t)m * N + n] = v;
                } else {
                    bf16_t bv = (bf16_t)v;
                    int b = m >> 11, s = m & (SS - 1);
                    int nn = n & (DD - 1);
                    int h = nn >> 7, d = nn & 127;
                    size_t off = (((size_t)b * HH + h) * SS + s) * HD + d;
                    if (n < DD)            Qw[off] = bv;
                    else if (n < 2 * DD)   Kw[off] = bv;
                    else                   Vw[off] = bv;
                }
            }
}

// ---------------------------------------------------------------------------
// In-place interleaved RoPE on Q and K, layout [b][h][s][d], fp32 math.
// ---------------------------------------------------------------------------
__global__ void rope_kernel(bf16_t* __restrict__ Qw, bf16_t* __restrict__ Kw) {
    int idx = blockIdx.x * 256 + threadIdx.x;   // < BB*HH*SS*64
    int i  = idx & 63;
    int s  = (idx >> 6) & (SS - 1);
    int bh = idx >> 17;
    float inv = expf(-(float)(2 * i) * (9.210340371976184f / 128.0f));
    float ang = (float)s * inv;
    float c = cosf(ang), sn = sinf(ang);
    size_t base = ((size_t)bh * SS + s) * HD + 2 * i;
    float q1 = (float)Qw[base], q2 = (float)Qw[base + 1];
    Qw[base]     = (bf16_t)(q1 * c - q2 * sn);
    Qw[base + 1] = (bf16_t)(q1 * sn + q2 * c);
    float k1 = (float)Kw[base], k2 = (float)Kw[base + 1];
    Kw[base]     = (bf16_t)(k1 * c - k2 * sn);
    Kw[base + 1] = (bf16_t)(k1 * sn + k2 * c);
}

// ---------------------------------------------------------------------------
// V transpose: Vw [bh][s][d] -> Vt [bh][d][s'], where s' is PERMUTED within
// each 64-s chunk so flash's PV B-operand reads the MFMA k-slot order that
// matches the in-register P fragments (no P LDS round-trip needed).
// Slot mapping: LDS/global position p = (k2:1)(lkq:2)(a:1)(b:2) holds
// s = (k2:1)(a:1)(lkq:2)(b:2).  64x64 tiles via LDS (pad 65), coalesced
// 16B+ on both global sides.  grid (SS/64, HD/64, BB*HH), block 256.
// ---------------------------------------------------------------------------
__global__ void vtrans_kernel(const bf16_t* __restrict__ Vw, bf16_t* __restrict__ Vt) {
    __shared__ unsigned short lds[64][65];
    const int t = threadIdx.x;
    const int s0 = blockIdx.x * 64, d0 = blockIdx.y * 64, bh = blockIdx.z;
    const bf16_t* src = Vw + ((size_t)bh * SS + s0) * HD + d0;
    bf16_t* dst = Vt + ((size_t)bh * HD + d0) * SS + s0;
#pragma unroll
    for (int p = 0; p < 2; ++p) {
        int c = p * 256 + t;
        int s = c >> 3, ch = c & 7;                  // 8 chunks of 16B per 64-d row
        uint4 v = *(const uint4*)(src + (size_t)s * HD + ch * 8);
        const unsigned short* pv = (const unsigned short*)&v;
#pragma unroll
        for (int e = 0; e < 8; ++e) lds[ch * 8 + e][s] = pv[e];
    }
    __syncthreads();
    {
        int d = t >> 2, sb = (t & 3) * 16;           // 16 s-elements = 32B per thread
        uint4 o[2];
        unsigned short* po = (unsigned short*)o;
#pragma unroll
        for (int e = 0; e < 16; ++e) {
            int p = sb + e;
            // p = (k2)(lkq:2)(a)(b:2)  ->  s = (k2)(a)(lkq:2)(b:2)
            int s = (p & ~31) | ((p & 4) << 2) | ((p & 24) >> 1) | (p & 3);
            po[e] = lds[d][s];
        }
        *(uint4*)(dst + (size_t)d * SS + sb) = o[0];
        *(uint4*)(dst + (size_t)d * SS + sb + 8) = o[1];
    }
}

// ---------------------------------------------------------------------------
// Causal flash attention, S^T formulation, PAIRED 64-q tiles + fragment reuse
// + register-P.
// Round-5 post-mortem: counted-vmcnt dbuf at 2 blk/CU (134us) LOST to plain
// sync at 4 blk/CU (115us) and even to R1's drain-all dbuf (120us) -> staging
// latency tricks are not the lever; steady wave concurrency x load balance is.
// R4's hidden flaw: grid (32,64)=1024 blocks at 4/CU -> co-resident blocks
// c,c+256,c+512,c+768 share blockIdx.x = SAME qtile = same duration; CU
// utilization ~ Sum(qtile+1)/32^2 = 51.6% (occupancy 20.5% = decaying tail).
// Round-6: pair long tile qA=16+bx with short tile qB=15-bx in ONE block ->
// every block = 33 q-set-chunks of compute, uniform across the grid.  Both
// q-sets consume the SAME staged K/V chunk (R0 fragment-reuse: one kf/vf
// ds_read feeds 2 MFMAs; act0 gates qB after its diagonal) -> halves LDS
// reads/MFMA and staging vs R4.  Register-P retained.  Grid (16,32)=512
// blocks = 2/CU steady, 8 waves/CU flat, every CU busy to the end.
// ---------------------------------------------------------------------------
__global__ __launch_bounds__(256, 2) void flash_attn_kernel(
    const bf16_t* __restrict__ Qw, const bf16_t* __restrict__ Kw,
    const bf16_t* __restrict__ Vtw, bf16_t* __restrict__ Attn) {
    __shared__ __align__(16) bf16_t Ks[64 * 128];    // [k][d], chunks swizzled
    __shared__ __align__(16) bf16_t Vs[128 * 64];    // [d][s'], chunks swizzled

    const int t = threadIdx.x;
    const int lane = t & 63;
    const int wave = t >> 6;
    const int lrow = lane & 15;
    const int lkq  = lane >> 4;
    const int bxp = blockIdx.x;                       // 0..15
    const int qBt = 15 - bxp;                         // short tile (qs=0)
    const int qAt = 16 + bxp;                         // long tile  (qs=1)
    const int bh = blockIdx.y;

    const bf16_t* Qbh = Qw + (size_t)bh * SS * HD;
    const bf16_t* Kbh = Kw + (size_t)bh * SS * HD;
    const bf16_t* Vbh = Vtw + (size_t)bh * HD * SS;

    const int qb[2] = { qBt * 64 + wave * 16, qAt * 64 + wave * 16 };

    // Q fragments (B-operand layout: n=lane&15=q, k=quad*8+j), scale*log2e folded
    const float qscale = 0.08838834764831845f * 1.4426950408889634f;
    bf16x8 qf[2][4];
#pragma unroll
    for (int qs = 0; qs < 2; ++qs)
#pragma unroll
        for (int kc4 = 0; kc4 < 4; ++kc4) {
            qf[qs][kc4] = *(const bf16x8*)(Qbh + (size_t)(qb[qs] + lrow) * HD + kc4 * 32 + lkq * 8);
#pragma unroll
            for (int e = 0; e < 8; ++e) qf[qs][kc4][e] = (bf16_t)((float)qf[qs][kc4][e] * qscale);
        }

    floatx4 oacc[2][8];
#pragma unroll
    for (int qs = 0; qs < 2; ++qs)
#pragma unroll
        for (int i = 0; i < 8; ++i) oacc[qs][i] = (floatx4)0.0f;
    float m_i[2] = { -1e30f, -1e30f };
    float l_i[2] = { 0.0f, 0.0f };

    const int nch = qAt + 1;
    for (int kc = 0; kc < nch; ++kc) {
        __syncthreads();
        // stage K chunk [64][128]: 4 rows (256B each) per instr
#pragma unroll
        for (int p = 0; p < 4; ++p) {
            int row = wave * 16 + p * 4 + (lane >> 4);
            int gch = (lane & 15) ^ (row & 7);
            gl2lds16(Kbh + (size_t)(kc * 64 + row) * HD + gch * 8,
                     Ks + (wave * 16 + p * 4) * 128);
        }
        // stage V^T chunk [128][64]: 8 rows (128B each) per instr
#pragma unroll
        for (int p = 0; p < 4; ++p) {
            int row = wave * 32 + p * 8 + (lane >> 3);
            int gch = (lane & 7) ^ (row & 7);
            gl2lds16(Vbh + (size_t)row * SS + kc * 64 + gch * 8,
                     Vs + (wave * 32 + p * 8) * 64);
        }
        __syncthreads();

        const bool act0 = (kc * 64 <= qb[0] + 15);   // qs=1 active for all kc<nch

        // S^T[64k x 16q] both q-sets: one kf read feeds two MFMAs
        floatx4 sacc[2][4];
#pragma unroll
        for (int qs = 0; qs < 2; ++qs)
#pragma unroll
            for (int i = 0; i < 4; ++i) sacc[qs][i] = (floatx4)0.0f;
#pragma unroll
        for (int nf = 0; nf < 4; ++nf)
#pragma unroll
            for (int kc4 = 0; kc4 < 4; ++kc4) {
                bf16x8 kf = *(const bf16x8*)(Ks + (nf * 16 + lrow) * 128 +
                                             (((kc4 * 4 + lkq) ^ (lrow & 7)) * 8));
                if (act0)
                    sacc[0][nf] = __builtin_amdgcn_mfma_f32_16x16x32_bf16(kf, qf[0][kc4], sacc[0][nf], 0, 0, 0);
                sacc[1][nf] = __builtin_amdgcn_mfma_f32_16x16x32_bf16(kf, qf[1][kc4], sacc[1][nf], 0, 0, 0);
            }

        // softmax per q-set; P A-fragments built by pure in-register convert:
        // pa[k2][j] = P[q=lrow][k=32*k2+16*(j>>2)+4*lkq+(j&3)] = sacc[2k2+(j>>2)][j&3]
        bf16x8 pa[2][2];
#pragma unroll
        for (int qs = 0; qs < 2; ++qs) {
            const int qbase = qb[qs];                 // wave-uniform
            if (qs == 0 && !act0) continue;

            const int qg = qbase + lrow;
            float mx = m_i[qs];
            if (kc * 64 + 63 > qbase) {
                // diagonal chunk: causal mask + max
#pragma unroll
                for (int nf = 0; nf < 4; ++nf)
#pragma unroll
                    for (int r = 0; r < 4; ++r) {
                        int kg = kc * 64 + nf * 16 + lkq * 4 + r;
                        float sv = (kg > qg) ? -1e30f : sacc[qs][nf][r];
                        sacc[qs][nf][r] = sv;
                        mx = fmaxf(mx, sv);
                    }
            } else {
#pragma unroll
                for (int nf = 0; nf < 4; ++nf)
#pragma unroll
                    for (int r = 0; r < 4; ++r) mx = fmaxf(mx, sacc[qs][nf][r]);
            }
            mx = fmaxf(mx, __shfl_xor(mx, 16));
            mx = fmaxf(mx, __shfl_xor(mx, 32));
            float alpha = exp2f(m_i[qs] - mx);
            m_i[qs] = mx;

            float rs = 0.0f;
#pragma unroll
            for (int nf = 0; nf < 4; ++nf)
#pragma unroll
                for (int r = 0; r < 4; ++r) {
                    float pv = exp2f(sacc[qs][nf][r] - mx);
                    sacc[qs][nf][r] = pv;
                    rs += pv;
                }
            rs += __shfl_xor(rs, 16);
            rs += __shfl_xor(rs, 32);
            l_i[qs] = l_i[qs] * alpha + rs;

            // rescale O only if some lane's max moved (exact: exp2f(0)==1)
            if (__ballot(alpha < 1.0f)) {
                float av[4];
#pragma unroll
                for (int r = 0; r < 4; ++r) av[r] = __shfl(alpha, lkq * 4 + r);
#pragma unroll
                for (int nf8 = 0; nf8 < 8; ++nf8)
#pragma unroll
                    for (int r = 0; r < 4; ++r) oacc[qs][nf8][r] *= av[r];
            }

            // in-register P -> A-fragment (slot order matches permuted V^T)
#pragma unroll
            for (int k2 = 0; k2 < 2; ++k2) {
                bf16x8 t8;
#pragma unroll
                for (int j = 0; j < 8; ++j)
                    t8[j] = (bf16_t)sacc[qs][2 * k2 + (j >> 2)][j & 3];
                pa[qs][k2] = t8;
            }
        }

        // PV both q-sets: one vf read feeds two MFMAs
#pragma unroll
        for (int nf8 = 0; nf8 < 8; ++nf8)
#pragma unroll
            for (int k2 = 0; k2 < 2; ++k2) {
                bf16x8 vf = *(const bf16x8*)(Vs + (nf8 * 16 + lrow) * 64 +
                                             (((k2 * 4 + lkq) ^ (lrow & 7)) * 8));
                if (act0)
                    oacc[0][nf8] = __builtin_amdgcn_mfma_f32_16x16x32_bf16(pa[0][k2], vf, oacc[0][nf8], 0, 0, 0);
                oacc[1][nf8] = __builtin_amdgcn_mfma_f32_16x16x32_bf16(pa[1][k2], vf, oacc[1][nf8], 0, 0, 0);
            }
    }

    // finalize: O /= l, write attn[b][s][h*128+d] (bf16)
    int bb = bh >> 4, h = bh & 15;
#pragma unroll
    for (int qs = 0; qs < 2; ++qs)
#pragma unroll
        for (int r = 0; r < 4; ++r) {
            float invl = 1.0f / __shfl(l_i[qs], lkq * 4 + r);
            int q = qb[qs] + lkq * 4 + r;
#pragma unroll
            for (int nf8 = 0; nf8 < 8; ++nf8)
                Attn[((size_t)bb * SS + q) * DD + h * HD + nf8 * 16 + lrow] =
                    (bf16_t)(oacc[qs][nf8][r] * invl);
        }
}

// ---------------------------------------------------------------------------
extern "C" void kernel_launch(void* const* d_in, const int* in_sizes, int n_in,
                              void* d_out, int out_size, void* d_ws, size_t ws_size,
                              hipStream_t stream) {
    const float* x  = (const float*)d_in[0];
    const float* Wq = (const float*)d_in[1];
    const float* Wk = (const float*)d_in[2];
    const float* Wv = (const float*)d_in[3];
    const float* Wo = (const float*)d_in[4];
    float* out = (float*)d_out;

    bf16_t* p = (bf16_t*)d_ws;
    bf16_t* Xb    = p; p += (size_t)BB * SS * DD;
    bf16_t* Wqkvt = p; p += (size_t)3 * DD * DD;
    bf16_t* Wot   = p; p += (size_t)DD * DD;
    bf16_t* Qw    = p; p += (size_t)BB * HH * SS * HD;
    bf16_t* Kw    = p; p += (size_t)BB * HH * SS * HD;
    bf16_t* Vtw   = p; p += (size_t)BB * HH * SS * HD;
    bf16_t* Attn  = p; p += (size_t)BB * SS * DD;
    // V natural layout lives in the Attn region (dead until flash writes it):
    bf16_t* Vw = Attn;

    cast_x_kernel<<<(BB * SS * DD / 4) / 256, 256, 0, stream>>>(x, Xb);

    dim3 tb(32, 8), tg(DD / 32, DD / 32);
    transpose_cast_kernel<<<tg, tb, 0, stream>>>(Wq, Wqkvt);
    transpose_cast_kernel<<<tg, tb, 0, stream>>>(Wk, Wqkvt + (size_t)DD * DD);
    transpose_cast_kernel<<<tg, tb, 0, stream>>>(Wv, Wqkvt + (size_t)2 * DD * DD);
    transpose_cast_kernel<<<tg, tb, 0, stream>>>(Wo, Wot);

    // QKV: [4096 x 2048] @ [2048 x 6144] -> Q/K/V (all natural [bh][s][d])
    gemm_bt_kernel<0><<<dim3(3 * DD / 128, BB * SS / 128), 256, 0, stream>>>(
        Xb, Wqkvt, nullptr, Qw, Kw, Vw, 3 * DD, DD);

    rope_kernel<<<(BB * HH * SS * 64) / 256, 256, 0, stream>>>(Qw, Kw);

    // V [bh][s][d] -> Vt [bh][d][s-permuted], coalesced LDS transpose
    vtrans_kernel<<<dim3(SS / 64, HD / 64, BB * HH), 256, 0, stream>>>(Vw, Vtw);

    // paired q-tiles (16+bx, 15-bx): 512 uniform-length blocks, 2/CU steady
    flash_attn_kernel<<<dim3(16, BB * HH), 256, 0, stream>>>(Qw, Kw, Vtw, Attn);

    // out = attn @ Wo : [4096 x 2048] @ [2048 x 2048] -> fp32
    gemm_bt_kernel<1><<<dim3(DD / 128, BB * SS / 128), 256, 0, stream>>>(
        Attn, Wot, out, nullptr, nullptr, nullptr, DD, DD);
}

// Round 8
// 389.158 us; speedup vs baseline: 1.1232x; 1.0077x over previous
//
#include <hip/hip_runtime.h>
#include <hip/hip_bf16.h>

// Problem constants
static constexpr int BB = 2;      // batch
static constexpr int SS = 2048;   // seq len
static constexpr int DD = 2048;   // model dim
static constexpr int HH = 16;     // heads
static constexpr int HD = 128;    // head dim

typedef __bf16 bf16_t;
typedef __bf16 bf16x8 __attribute__((ext_vector_type(8)));
typedef __bf16 bf16x4 __attribute__((ext_vector_type(4)));
typedef float  floatx4 __attribute__((ext_vector_type(4)));

// scale * log2e folded into Q at the QKV epilogue (flash consumes pre-scaled Q)
static constexpr float QSC = 0.08838834764831845f * 1.4426950408889634f;

// Async global->LDS, 16B per lane. LDS dest is wave-uniform base + lane*16.
__device__ __forceinline__ void gl2lds16(const bf16_t* g, bf16_t* l) {
    __builtin_amdgcn_global_load_lds(
        (const __attribute__((address_space(1))) void*)g,
        (__attribute__((address_space(3))) void*)l, 16, 0, 0);
}

// ---------------------------------------------------------------------------
// Cast x (fp32) -> bf16, vectorized 4 elements/thread
// ---------------------------------------------------------------------------
__global__ void cast_x_kernel(const float* __restrict__ x, bf16_t* __restrict__ xb) {
    int i = blockIdx.x * 256 + threadIdx.x;
    float4 v = ((const float4*)x)[i];
    bf16x4 o;
    o.x = (bf16_t)v.x; o.y = (bf16_t)v.y; o.z = (bf16_t)v.z; o.w = (bf16_t)v.w;
    ((bf16x4*)xb)[i] = o;
}

// ---------------------------------------------------------------------------
// Transpose + cast all 4 DxD fp32 weights into bf16 W^T in ONE launch.
// blockIdx.z selects the weight (0..2 -> Wqkvt slabs, 3 -> Wot).
// block (32,8), grid (D/32, D/32, 4)
// ---------------------------------------------------------------------------
__global__ void transpose_cast4_kernel(const float* __restrict__ Wq,
                                       const float* __restrict__ Wk,
                                       const float* __restrict__ Wv,
                                       const float* __restrict__ Wo,
                                       bf16_t* __restrict__ Wqkvt,
                                       bf16_t* __restrict__ Wot) {
    __shared__ float tile[32][33];
    const int z = blockIdx.z;
    const float* W = (z == 0) ? Wq : (z == 1) ? Wk : (z == 2) ? Wv : Wo;
    bf16_t* Wt = (z == 3) ? Wot : Wqkvt + (size_t)z * DD * DD;
    int bx = blockIdx.x * 32;   // n
    int by = blockIdx.y * 32;   // k
    int tx = threadIdx.x, ty = threadIdx.y;
#pragma unroll
    for (int j = 0; j < 4; ++j)
        tile[ty + j * 8][tx] = W[(size_t)(by + ty + j * 8) * DD + bx + tx];
    __syncthreads();
#pragma unroll
    for (int j = 0; j < 4; ++j)
        Wt[(size_t)(bx + ty + j * 8) * DD + by + tx] = (bf16_t)tile[tx][ty + j * 8];
}

// ---------------------------------------------------------------------------
// bf16 GEMM, C[M x N] = A[M x K] @ Bt[N x K]^T.  128x128 tile, 256 threads,
// m97 structure: unpadded 128x64 LDS tiles staged via global_load_lds w=16,
// XOR chunk swizzle so ds_read_b128 hits the 8-beat minimum.
// MODE 0: QKV epilogue -> FUSED interleaved RoPE on Q/K (pair (d,d+1) sits in
//         adjacent lanes: partner via __shfl_xor(v,1); class Q/K/V is
//         block-uniform since n0 % 128 == 0 so V-blocks skip the trig), Q
//         pre-scaled by QSC, scatter bf16 Q/K/V [b][h][s][d].  Rope on the
//         fp32 accumulator BEFORE the single bf16 rounding (more accurate
//         than the old separate bf16 RMW rope pass, which this replaces).
// MODE 1: plain fp32 epilogue -> Cf[m*N+n]
// ---------------------------------------------------------------------------
template <int MODE>
__global__ __launch_bounds__(256, 2) void gemm_bt_kernel(
    const bf16_t* __restrict__ A, const bf16_t* __restrict__ Bt,
    float* __restrict__ Cf, bf16_t* __restrict__ Qw, bf16_t* __restrict__ Kw,
    bf16_t* __restrict__ Vw, int N, int K) {
    __shared__ __align__(16) bf16_t As[128 * 64];
    __shared__ __align__(16) bf16_t Bs[128 * 64];

    const int t = threadIdx.x;
    const int lane = t & 63;
    const int wave = t >> 6;
    const int lrow = lane & 15;   // m (A) / n (B) within 16
    const int lkq  = lane >> 4;   // k-quad
    const int wm = (wave & 1) * 64;
    const int wn = (wave >> 1) * 64;
    const int m0 = blockIdx.y * 128;
    const int n0 = blockIdx.x * 128;

    floatx4 acc[4][4];
#pragma unroll
    for (int i = 0; i < 4; ++i)
#pragma unroll
        for (int j = 0; j < 4; ++j) acc[i][j] = (floatx4)0.0f;

    // staging geometry: per instr a wave moves 8 rows x 64 cols (1024B).
    const int srow  = lane >> 3;                    // row within 8
    const int sch   = (lane & 7) ^ srow;            // swizzled global chunk

    for (int k0 = 0; k0 < K; k0 += 64) {
        __syncthreads();
#pragma unroll
        for (int p = 0; p < 4; ++p) {
            int r = wave * 32 + p * 8 + srow;
            gl2lds16(A  + (size_t)(m0 + r) * K + k0 + sch * 8, As + (wave * 32 + p * 8) * 64);
            gl2lds16(Bt + (size_t)(n0 + r) * K + k0 + sch * 8, Bs + (wave * 32 + p * 8) * 64);
        }
        __syncthreads();
#pragma unroll
        for (int ks = 0; ks < 2; ++ks) {
            bf16x8 af[4], bg[4];
#pragma unroll
            for (int i = 0; i < 4; ++i) {
                int pos = ((ks * 4 + lkq) ^ (lrow & 7)) * 8;
                af[i] = *(const bf16x8*)(As + (wm + i * 16 + lrow) * 64 + pos);
                bg[i] = *(const bf16x8*)(Bs + (wn + i * 16 + lrow) * 64 + pos);
            }
#pragma unroll
            for (int i = 0; i < 4; ++i)
#pragma unroll
                for (int j = 0; j < 4; ++j)
                    acc[i][j] = __builtin_amdgcn_mfma_f32_16x16x32_bf16(af[i], bg[j], acc[i][j], 0, 0, 0);
        }
    }

    // Epilogue. C/D layout (verified m89): col = lane&15, row = (lane>>4)*4 + reg.
#pragma unroll
    for (int i = 0; i < 4; ++i)
#pragma unroll
        for (int j = 0; j < 4; ++j)
#pragma unroll
            for (int r = 0; r < 4; ++r) {
                int m = m0 + wm + i * 16 + lkq * 4 + r;
                int n = n0 + wn + j * 16 + lrow;
                float v = acc[i][j][r];
                if (MODE == 1) {
                    Cf[(size_t)m * N + n] = v;
                } else {
                    int b = m >> 11, s = m & (SS - 1);
                    int nn = n & (DD - 1);
                    int h = nn >> 7, d = nn & 127;
                    size_t off = (((size_t)b * HH + h) * SS + s) * HD + d;
                    if (n < 2 * DD) {
                        // fused interleaved RoPE; partner value from lane^1
                        float vp = __shfl_xor(v, 1);
                        float inv = __expf(-0.07195578415f * (float)(d & 126));
                        float ang = (float)s * inv;
                        float c = __cosf(ang), sn = __sinf(ang);
                        float ro = (d & 1) ? (vp * sn + v * c) : (v * c - vp * sn);
                        if (n < DD) Qw[off] = (bf16_t)(ro * QSC);
                        else        Kw[off] = (bf16_t)ro;
                    } else {
                        Vw[off] = (bf16_t)v;
                    }
                }
            }
}

// ---------------------------------------------------------------------------
// V transpose: Vw [bh][s][d] -> Vt [bh][d][s'], where s' is PERMUTED within
// each 64-s chunk so flash's PV B-operand reads the MFMA k-slot order that
// matches the in-register P fragments (no P LDS round-trip needed).
// Slot mapping: LDS/global position p = (k2:1)(lkq:2)(a:1)(b:2) holds
// s = (k2:1)(a:1)(lkq:2)(b:2).  64x64 tiles via LDS (pad 65), coalesced
// 16B+ on both global sides.  grid (SS/64, HD/64, BB*HH), block 256.
// ---------------------------------------------------------------------------
__global__ void vtrans_kernel(const bf16_t* __restrict__ Vw, bf16_t* __restrict__ Vt) {
    __shared__ unsigned short lds[64][65];
    const int t = threadIdx.x;
    const int s0 = blockIdx.x * 64, d0 = blockIdx.y * 64, bh = blockIdx.z;
    const bf16_t* src = Vw + ((size_t)bh * SS + s0) * HD + d0;
    bf16_t* dst = Vt + ((size_t)bh * HD + d0) * SS + s0;
#pragma unroll
    for (int p = 0; p < 2; ++p) {
        int c = p * 256 + t;
        int s = c >> 3, ch = c & 7;                  // 8 chunks of 16B per 64-d row
        uint4 v = *(const uint4*)(src + (size_t)s * HD + ch * 8);
        const unsigned short* pv = (const unsigned short*)&v;
#pragma unroll
        for (int e = 0; e < 8; ++e) lds[ch * 8 + e][s] = pv[e];
    }
    __syncthreads();
    {
        int d = t >> 2, sb = (t & 3) * 16;           // 16 s-elements = 32B per thread
        uint4 o[2];
        unsigned short* po = (unsigned short*)o;
#pragma unroll
        for (int e = 0; e < 16; ++e) {
            int p = sb + e;
            // p = (k2)(lkq:2)(a)(b:2)  ->  s = (k2)(a)(lkq:2)(b:2)
            int s = (p & ~31) | ((p & 4) << 2) | ((p & 24) >> 1) | (p & 3);
            po[e] = lds[d][s];
        }
        *(uint4*)(dst + (size_t)d * SS + sb) = o[0];
        *(uint4*)(dst + (size_t)d * SS + sb + 8) = o[1];
    }
}

// ---------------------------------------------------------------------------
// Causal flash attention, S^T formulation, PAIRED 64-q tiles + fragment reuse
// + register-P.  (R6 structure, best measured: flash dropped out of top-5.)
// Pair long tile qA=16+bx with short tile qB=15-bx in ONE block -> every
// block = 33 q-set-chunks of compute, uniform across the grid.  Both q-sets
// consume the SAME staged K/V chunk (one kf/vf ds_read feeds 2 MFMAs; act0
// gates qB after its diagonal).  Register-P: PV A-fragment is a pure
// in-register convert of sacc (k-slot mapping k=32*k2+16*(j>>2)+4*lkq+(j&3)),
// matched by the s-permuted V^T from vtrans.  Grid (16,32)=512 blocks = 2/CU
// steady, 8 waves/CU flat.  Q arrives PRE-SCALED by QSC from the QKV epilogue
// (per-fragment scaling loop deleted).
// ---------------------------------------------------------------------------
__global__ __launch_bounds__(256, 2) void flash_attn_kernel(
    const bf16_t* __restrict__ Qw, const bf16_t* __restrict__ Kw,
    const bf16_t* __restrict__ Vtw, bf16_t* __restrict__ Attn) {
    __shared__ __align__(16) bf16_t Ks[64 * 128];    // [k][d], chunks swizzled
    __shared__ __align__(16) bf16_t Vs[128 * 64];    // [d][s'], chunks swizzled

    const int t = threadIdx.x;
    const int lane = t & 63;
    const int wave = t >> 6;
    const int lrow = lane & 15;
    const int lkq  = lane >> 4;
    const int bxp = blockIdx.x;                       // 0..15
    const int qBt = 15 - bxp;                         // short tile (qs=0)
    const int qAt = 16 + bxp;                         // long tile  (qs=1)
    const int bh = blockIdx.y;

    const bf16_t* Qbh = Qw + (size_t)bh * SS * HD;
    const bf16_t* Kbh = Kw + (size_t)bh * SS * HD;
    const bf16_t* Vbh = Vtw + (size_t)bh * HD * SS;

    const int qb[2] = { qBt * 64 + wave * 16, qAt * 64 + wave * 16 };

    // Q fragments (B-operand layout: n=lane&15=q, k=quad*8+j); pre-scaled.
    bf16x8 qf[2][4];
#pragma unroll
    for (int qs = 0; qs < 2; ++qs)
#pragma unroll
        for (int kc4 = 0; kc4 < 4; ++kc4)
            qf[qs][kc4] = *(const bf16x8*)(Qbh + (size_t)(qb[qs] + lrow) * HD + kc4 * 32 + lkq * 8);

    floatx4 oacc[2][8];
#pragma unroll
    for (int qs = 0; qs < 2; ++qs)
#pragma unroll
        for (int i = 0; i < 8; ++i) oacc[qs][i] = (floatx4)0.0f;
    float m_i[2] = { -1e30f, -1e30f };
    float l_i[2] = { 0.0f, 0.0f };

    const int nch = qAt + 1;
    for (int kc = 0; kc < nch; ++kc) {
        __syncthreads();
        // stage K chunk [64][128]: 4 rows (256B each) per instr
#pragma unroll
        for (int p = 0; p < 4; ++p) {
            int row = wave * 16 + p * 4 + (lane >> 4);
            int gch = (lane & 15) ^ (row & 7);
            gl2lds16(Kbh + (size_t)(kc * 64 + row) * HD + gch * 8,
                     Ks + (wave * 16 + p * 4) * 128);
        }
        // stage V^T chunk [128][64]: 8 rows (128B each) per instr
#pragma unroll
        for (int p = 0; p < 4; ++p) {
            int row = wave * 32 + p * 8 + (lane >> 3);
            int gch = (lane & 7) ^ (row & 7);
            gl2lds16(Vbh + (size_t)row * SS + kc * 64 + gch * 8,
                     Vs + (wave * 32 + p * 8) * 64);
        }
        __syncthreads();

        const bool act0 = (kc * 64 <= qb[0] + 15);   // qs=1 active for all kc<nch

        // S^T[64k x 16q] both q-sets: one kf read feeds two MFMAs
        floatx4 sacc[2][4];
#pragma unroll
        for (int qs = 0; qs < 2; ++qs)
#pragma unroll
            for (int i = 0; i < 4; ++i) sacc[qs][i] = (floatx4)0.0f;
#pragma unroll
        for (int nf = 0; nf < 4; ++nf)
#pragma unroll
            for (int kc4 = 0; kc4 < 4; ++kc4) {
                bf16x8 kf = *(const bf16x8*)(Ks + (nf * 16 + lrow) * 128 +
                                             (((kc4 * 4 + lkq) ^ (lrow & 7)) * 8));
                if (act0)
                    sacc[0][nf] = __builtin_amdgcn_mfma_f32_16x16x32_bf16(kf, qf[0][kc4], sacc[0][nf], 0, 0, 0);
                sacc[1][nf] = __builtin_amdgcn_mfma_f32_16x16x32_bf16(kf, qf[1][kc4], sacc[1][nf], 0, 0, 0);
            }

        // softmax per q-set; P A-fragments built by pure in-register convert:
        // pa[k2][j] = P[q=lrow][k=32*k2+16*(j>>2)+4*lkq+(j&3)] = sacc[2k2+(j>>2)][j&3]
        bf16x8 pa[2][2];
#pragma unroll
        for (int qs = 0; qs < 2; ++qs) {
            const int qbase = qb[qs];                 // wave-uniform
            if (qs == 0 && !act0) continue;

            const int qg = qbase + lrow;
            float mx = m_i[qs];
            if (kc * 64 + 63 > qbase) {
                // diagonal chunk: causal mask + max
#pragma unroll
                for (int nf = 0; nf < 4; ++nf)
#pragma unroll
                    for (int r = 0; r < 4; ++r) {
                        int kg = kc * 64 + nf * 16 + lkq * 4 + r;
                        float sv = (kg > qg) ? -1e30f : sacc[qs][nf][r];
                        sacc[qs][nf][r] = sv;
                        mx = fmaxf(mx, sv);
                    }
            } else {
#pragma unroll
                for (int nf = 0; nf < 4; ++nf)
#pragma unroll
                    for (int r = 0; r < 4; ++r) mx = fmaxf(mx, sacc[qs][nf][r]);
            }
            mx = fmaxf(mx, __shfl_xor(mx, 16));
            mx = fmaxf(mx, __shfl_xor(mx, 32));
            float alpha = exp2f(m_i[qs] - mx);
            m_i[qs] = mx;

            float rs = 0.0f;
#pragma unroll
            for (int nf = 0; nf < 4; ++nf)
#pragma unroll
                for (int r = 0; r < 4; ++r) {
                    float pv = exp2f(sacc[qs][nf][r] - mx);
                    sacc[qs][nf][r] = pv;
                    rs += pv;
                }
            rs += __shfl_xor(rs, 16);
            rs += __shfl_xor(rs, 32);
            l_i[qs] = l_i[qs] * alpha + rs;

            // rescale O only if some lane's max moved (exact: exp2f(0)==1)
            if (__ballot(alpha < 1.0f)) {
                float av[4];
#pragma unroll
                for (int r = 0; r < 4; ++r) av[r] = __shfl(alpha, lkq * 4 + r);
#pragma unroll
                for (int nf8 = 0; nf8 < 8; ++nf8)
#pragma unroll
                    for (int r = 0; r < 4; ++r) oacc[qs][nf8][r] *= av[r];
            }

            // in-register P -> A-fragment (slot order matches permuted V^T)
#pragma unroll
            for (int k2 = 0; k2 < 2; ++k2) {
                bf16x8 t8;
#pragma unroll
                for (int j = 0; j < 8; ++j)
                    t8[j] = (bf16_t)sacc[qs][2 * k2 + (j >> 2)][j & 3];
                pa[qs][k2] = t8;
            }
        }

        // PV both q-sets: one vf read feeds two MFMAs
#pragma unroll
        for (int nf8 = 0; nf8 < 8; ++nf8)
#pragma unroll
            for (int k2 = 0; k2 < 2; ++k2) {
                bf16x8 vf = *(const bf16x8*)(Vs + (nf8 * 16 + lrow) * 64 +
                                             (((k2 * 4 + lkq) ^ (lrow & 7)) * 8));
                if (act0)
                    oacc[0][nf8] = __builtin_amdgcn_mfma_f32_16x16x32_bf16(pa[0][k2], vf, oacc[0][nf8], 0, 0, 0);
                oacc[1][nf8] = __builtin_amdgcn_mfma_f32_16x16x32_bf16(pa[1][k2], vf, oacc[1][nf8], 0, 0, 0);
            }
    }

    // finalize: O /= l, write attn[b][s][h*128+d] (bf16)
    int bb = bh >> 4, h = bh & 15;
#pragma unroll
    for (int qs = 0; qs < 2; ++qs)
#pragma unroll
        for (int r = 0; r < 4; ++r) {
            float invl = 1.0f / __shfl(l_i[qs], lkq * 4 + r);
            int q = qb[qs] + lkq * 4 + r;
#pragma unroll
            for (int nf8 = 0; nf8 < 8; ++nf8)
                Attn[((size_t)bb * SS + q) * DD + h * HD + nf8 * 16 + lrow] =
                    (bf16_t)(oacc[qs][nf8][r] * invl);
        }
}

// ---------------------------------------------------------------------------
extern "C" void kernel_launch(void* const* d_in, const int* in_sizes, int n_in,
                              void* d_out, int out_size, void* d_ws, size_t ws_size,
                              hipStream_t stream) {
    const float* x  = (const float*)d_in[0];
    const float* Wq = (const float*)d_in[1];
    const float* Wk = (const float*)d_in[2];
    const float* Wv = (const float*)d_in[3];
    const float* Wo = (const float*)d_in[4];
    float* out = (float*)d_out;

    bf16_t* p = (bf16_t*)d_ws;
    bf16_t* Xb    = p; p += (size_t)BB * SS * DD;
    bf16_t* Wqkvt = p; p += (size_t)3 * DD * DD;
    bf16_t* Wot   = p; p += (size_t)DD * DD;
    bf16_t* Qw    = p; p += (size_t)BB * HH * SS * HD;
    bf16_t* Kw    = p; p += (size_t)BB * HH * SS * HD;
    bf16_t* Vtw   = p; p += (size_t)BB * HH * SS * HD;
    bf16_t* Attn  = p; p += (size_t)BB * SS * DD;
    // V natural layout lives in the Attn region (dead until flash writes it):
    bf16_t* Vw = Attn;

    cast_x_kernel<<<(BB * SS * DD / 4) / 256, 256, 0, stream>>>(x, Xb);

    // all 4 weight transposes in one launch
    transpose_cast4_kernel<<<dim3(DD / 32, DD / 32, 4), dim3(32, 8), 0, stream>>>(
        Wq, Wk, Wv, Wo, Wqkvt, Wot);

    // QKV: [4096 x 2048] @ [2048 x 6144] -> Q/K/V with FUSED RoPE + Q pre-scale
    gemm_bt_kernel<0><<<dim3(3 * DD / 128, BB * SS / 128), 256, 0, stream>>>(
        Xb, Wqkvt, nullptr, Qw, Kw, Vw, 3 * DD, DD);

    // V [bh][s][d] -> Vt [bh][d][s-permuted], coalesced LDS transpose
    vtrans_kernel<<<dim3(SS / 64, HD / 64, BB * HH), 256, 0, stream>>>(Vw, Vtw);

    // paired q-tiles (16+bx, 15-bx): 512 uniform-length blocks, 2/CU steady
    flash_attn_kernel<<<dim3(16, BB * HH), 256, 0, stream>>>(Qw, Kw, Vtw, Attn);

    // out = attn @ Wo : [4096 x 2048] @ [2048 x 2048] -> fp32
    gemm_bt_kernel<1><<<dim3(DD / 128, BB * SS / 128), 256, 0, stream>>>(
        Attn, Wot, out, nullptr, nullptr, nullptr, DD, DD);
}